// Round 8
// baseline (86.077 us; speedup 1.0000x reference)
//
#include <hip/hip_runtime.h>

#define PIMG 1024   // H*W = 32*32
#define CCH  128    // channels
#define KG   68     // clusters incl. ghost
#define KR   64     // real clusters
#define T1   32     // pixels per block (kernel 1)

typedef float f4v __attribute__((ext_vector_type(4)));

// ---------------- Kernel 1: norms + logits + softmax ----------------
// grid: N*32 blocks (32 pixels each), 256 threads. LDS ~26 KB.
__global__ __launch_bounds__(256) void nv_assign_kernel(
    const float* __restrict__ x,       // [N,128,1024]
    const float* __restrict__ conv_w,  // [68,128]
    float* __restrict__ sa_out,        // [N,68,1024]
    float* __restrict__ rnorm_ws)      // [N*1024]
{
    __shared__ float xs[CCH * T1];   // raw x tile, [c][pix]  16 KB
    __shared__ float lg[KG * T1];    // logits→exp, [k][pix]  8.5 KB
    __shared__ float red[8 * T1];    // reduction scratch
    __shared__ float rn_l[T1];
    __shared__ float mx_l[T1];
    __shared__ float is_l[T1];

    const int t   = threadIdx.x;
    const int gp0 = blockIdx.x * T1;
    const int n   = gp0 >> 10;
    const int p0  = gp0 & 1023;

    // stage raw x tile (coalesced)
    const float* xb = x + (size_t)n * (CCH * PIMG) + p0;
    for (int i = t; i < CCH * T1; i += 256)
        xs[i] = xb[(i >> 5) * PIMG + (i & 31)];
    __syncthreads();

    // sum of squares: 8 threads per pixel, 16 channels each
    {
        int pix = t & 31, q = t >> 5;
        float s = 0.f;
        #pragma unroll
        for (int c = q * 16; c < q * 16 + 16; ++c) {
            float v = xs[c * T1 + pix];
            s += v * v;
        }
        red[q * T1 + pix] = s;
    }
    __syncthreads();
    if (t < T1) {
        float s = 0.f;
        #pragma unroll
        for (int q = 0; q < 8; ++q) s += red[q * T1 + t];
        float r = 1.0f / fmaxf(sqrtf(s), 1e-12f);
        rn_l[t] = r;
        rnorm_ws[gp0 + t] = r;
    }
    __syncthreads();

    // logits: tasks = (k-pair, pix4-group) = 34*8 = 272
    for (int task = t; task < (KG / 2) * (T1 / 4); task += 256) {
        int g  = task & 7;
        int k0 = (task >> 3) << 1;
        const float* w0 = conv_w + k0 * CCH;
        const float* w1 = w0 + CCH;
        f4v a0 = {0.f, 0.f, 0.f, 0.f}, a1 = {0.f, 0.f, 0.f, 0.f};
        #pragma unroll 8
        for (int c = 0; c < CCH; ++c) {
            f4v xv = *(const f4v*)(xs + c * T1 + g * 4);
            float wv0 = w0[c], wv1 = w1[c];
            a0 += xv * wv0;
            a1 += xv * wv1;
        }
        f4v r4 = *(const f4v*)(rn_l + g * 4);
        *(f4v*)(lg + k0 * T1 + g * 4)       = a0 * r4;
        *(f4v*)(lg + (k0 + 1) * T1 + g * 4) = a1 * r4;
    }
    __syncthreads();

    // softmax over k: 8 threads per pixel
    {
        int pix = t & 31, q = t >> 5;
        float m = -1e30f;
        for (int k = q; k < KG; k += 8) m = fmaxf(m, lg[k * T1 + pix]);
        red[q * T1 + pix] = m;
    }
    __syncthreads();
    if (t < T1) {
        float m = red[t];
        #pragma unroll
        for (int q = 1; q < 8; ++q) m = fmaxf(m, red[q * T1 + t]);
        mx_l[t] = m;
    }
    __syncthreads();
    {
        int pix = t & 31, q = t >> 5;
        float m = mx_l[pix], s = 0.f;
        for (int k = q; k < KG; k += 8) {
            float e = expf(lg[k * T1 + pix] - m);
            lg[k * T1 + pix] = e;
            s += e;
        }
        red[q * T1 + pix] = s;
    }
    __syncthreads();
    if (t < T1) {
        float s = 0.f;
        #pragma unroll
        for (int q = 0; q < 8; ++q) s += red[q * T1 + t];
        is_l[t] = 1.0f / s;
    }
    __syncthreads();

    // write soft_assign (coalesced over pix)
    for (int i = t; i < KG * T1; i += 256) {
        int k = i >> 5, pix = i & 31;
        sa_out[((size_t)n * KG + k) * PIMG + p0 + pix] = lg[i] * is_l[pix];
    }
}

// ---------------- Kernel 2: streaming residual write (R4 best) -------------
// grid: N*64*4 blocks, one per (n, k, c-quarter); 256 threads; thread owns 4
// pixels. Plain stores.
__global__ __launch_bounds__(256) void nv_resid_kernel(
    const float* __restrict__ x,          // [N,128,1024]
    const float* __restrict__ centroids,  // [68,128]
    const float* __restrict__ sa,         // [N,68,1024]
    const float* __restrict__ rnorm,      // [N,1024]
    float* __restrict__ out)              // [N,64,128,1024]
{
    const int b  = blockIdx.x;
    const int n  = b >> 8;
    const int k  = (b >> 2) & 63;
    const int c0 = (b & 3) << 5;
    const int t  = threadIdx.x;

    const f4v rn4 = ((const f4v*)(rnorm + (size_t)n * PIMG))[t];
    const f4v a4  = ((const f4v*)(sa + ((size_t)n * KG + k) * PIMG))[t];
    const f4v ra  = rn4 * a4;   // out = x*(rn*a) - cent*a

    const float* cw = centroids + k * CCH + c0;      // uniform -> s_load
    const float* xb = x + (size_t)n * (CCH * PIMG) + (size_t)c0 * PIMG;
    float* ob = out + (((size_t)n * KR + k) * CCH + c0) * PIMG;

    #pragma unroll 8
    for (int c = 0; c < 32; ++c) {
        f4v xv = ((const f4v*)(xb + c * PIMG))[t];
        float ce = cw[c];
        f4v o = xv * ra - ce * a4;
        ((f4v*)(ob + c * PIMG))[t] = o;
    }
}

extern "C" void kernel_launch(void* const* d_in, const int* in_sizes, int n_in,
                              void* d_out, int out_size, void* d_ws, size_t ws_size,
                              hipStream_t stream) {
    const float* x         = (const float*)d_in[0];
    const float* conv_w    = (const float*)d_in[1];
    const float* centroids = (const float*)d_in[2];

    const int N = in_sizes[0] / (CCH * PIMG);   // 8

    float* out    = (float*)d_out;
    float* sa_out = out + (size_t)N * KR * CCH * PIMG;  // second tuple element
    float* rnorm  = (float*)d_ws;                        // N*1024 floats

    // INSTRUMENTATION ROUND: k1 launched 3x (idempotent, deterministic).
    // total = 3*k1 + k2; R4 gave k1 + k2 = 63.1 us  =>  k1 = (total-63.1)/2.
    nv_assign_kernel<<<N * (PIMG / T1), 256, 0, stream>>>(x, conv_w, sa_out, rnorm);
    nv_assign_kernel<<<N * (PIMG / T1), 256, 0, stream>>>(x, conv_w, sa_out, rnorm);
    nv_assign_kernel<<<N * (PIMG / T1), 256, 0, stream>>>(x, conv_w, sa_out, rnorm);
    nv_resid_kernel<<<N * KR * 4, 256, 0, stream>>>(x, centroids, sa_out, rnorm, out);
}

// Round 9
// 62.127 us; speedup vs baseline: 1.3855x; 1.3855x over previous
//
#include <hip/hip_runtime.h>

#define PIMG 1024   // H*W = 32*32
#define CCH  128    // channels
#define KG   68     // clusters incl. ghost
#define KR   64     // real clusters
#define T1   32     // pixels per block (kernel 1)
#define WP   132    // w_lds row pitch (floats): banks (4k+c)%32 -> conflict-free octets
#define LP   33     // lg row pitch

typedef float f4v __attribute__((ext_vector_type(4)));

// ---------------- Kernel 1: norms + logits + softmax (v2) ----------------
// grid: N*32 blocks (32 pixels each), 512 threads (8 waves, 2/SIMD).
// conv_w staged in padded LDS; logit loop: wave-uniform k-octets, zero global
// loads, conflict-free b128 LDS reads. LDS ~62 KB.
__global__ __launch_bounds__(512) void nv_assign_kernel(
    const float* __restrict__ x,       // [N,128,1024]
    const float* __restrict__ conv_w,  // [68,128]
    float* __restrict__ sa_out,        // [N,68,1024]
    float* __restrict__ rnorm_ws)      // [N*1024]
{
    __shared__ float xs[CCH * T1];   // raw x tile [c][pix]   16 KB
    __shared__ float wl[KG * WP];    // padded conv_w         35.9 KB
    __shared__ float lg[KG * LP];    // logits -> exp         9 KB
    __shared__ float red[16 * T1];   // reduction scratch     2 KB
    __shared__ float rn_l[T1];
    __shared__ float mx_l[T1];
    __shared__ float is_l[T1];

    const int t   = threadIdx.x;
    const int gp0 = blockIdx.x * T1;
    const int n   = gp0 >> 10;
    const int p0  = gp0 & 1023;

    // stage conv_w into padded LDS (f4 chunks, coalesced)
    for (int i = t; i < KG * (CCH / 4); i += 512) {
        int k = i >> 5, c4 = i & 31;
        *(f4v*)(wl + k * WP + c4 * 4) = ((const f4v*)(conv_w + k * CCH))[c4];
    }
    // stage x tile (f4 over pixels, coalesced)
    const float* xb = x + (size_t)n * (CCH * PIMG) + p0;
    for (int i = t; i < CCH * (T1 / 4); i += 512) {
        int c = i >> 3, p4 = i & 7;
        *(f4v*)(xs + c * T1 + p4 * 4) = *(const f4v*)(xb + c * PIMG + p4 * 4);
    }
    __syncthreads();

    // norms: 16 threads per pixel, 8 channels each
    {
        int pix = t & 31, q = t >> 5;
        float s = 0.f;
        #pragma unroll
        for (int c = q * 8; c < q * 8 + 8; ++c) {
            float v = xs[c * T1 + pix];
            s += v * v;
        }
        red[q * T1 + pix] = s;
    }
    __syncthreads();
    if (t < T1) {
        float s = 0.f;
        #pragma unroll
        for (int q = 0; q < 16; ++q) s += red[q * T1 + t];
        float r = 1.0f / fmaxf(sqrtf(s), 1e-12f);
        rn_l[t] = r;
        rnorm_ws[gp0 + t] = r;
    }
    __syncthreads();

    // logits: task = (k, pix4-group); 544 tasks, wave-uniform k octets.
    // xs b128: 8 distinct addrs (banks 4g..4g+3) with 8-way k-broadcast;
    // wl b128: octet k -> start banks 4k%32 partition all 32 banks.
    for (int task = t; task < KG * 8; task += 512) {
        int g = task & 7, k = task >> 3;
        const float* wr = wl + k * WP;
        const float* xr = xs + g * 4;
        f4v acc = {0.f, 0.f, 0.f, 0.f};
        #pragma unroll 8
        for (int c0 = 0; c0 < CCH; c0 += 4) {
            f4v w4 = *(const f4v*)(wr + c0);
            acc += *(const f4v*)(xr + (c0 + 0) * T1) * w4.x;
            acc += *(const f4v*)(xr + (c0 + 1) * T1) * w4.y;
            acc += *(const f4v*)(xr + (c0 + 2) * T1) * w4.z;
            acc += *(const f4v*)(xr + (c0 + 3) * T1) * w4.w;
        }
        f4v r4 = *(const f4v*)(rn_l + g * 4);
        acc *= r4;
        float* lr = lg + k * LP + g * 4;   // pitch 33: <=2-way conflict (free)
        lr[0] = acc.x; lr[1] = acc.y; lr[2] = acc.z; lr[3] = acc.w;
    }
    __syncthreads();

    // softmax over k: 16 threads per pixel
    {
        int pix = t & 31, q = t >> 5;
        float m = -1e30f;
        for (int k = q; k < KG; k += 16) m = fmaxf(m, lg[k * LP + pix]);
        red[q * T1 + pix] = m;
    }
    __syncthreads();
    if (t < T1) {
        float m = red[t];
        #pragma unroll
        for (int q = 1; q < 16; ++q) m = fmaxf(m, red[q * T1 + t]);
        mx_l[t] = m;
    }
    __syncthreads();
    {
        int pix = t & 31, q = t >> 5;
        float m = mx_l[pix], s = 0.f;
        for (int k = q; k < KG; k += 16) {
            float e = expf(lg[k * LP + pix] - m);
            lg[k * LP + pix] = e;
            s += e;
        }
        red[q * T1 + pix] = s;
    }
    __syncthreads();
    if (t < T1) {
        float s = 0.f;
        #pragma unroll
        for (int q = 0; q < 16; ++q) s += red[q * T1 + t];
        is_l[t] = 1.0f / s;
    }
    __syncthreads();

    // write soft_assign (coalesced over pix)
    for (int i = t; i < KG * T1; i += 512) {
        int k = i >> 5, pix = i & 31;
        sa_out[((size_t)n * KG + k) * PIMG + p0 + pix] = lg[k * LP + pix] * is_l[pix];
    }
}

// ---------------- Kernel 2: streaming residual write (R4 best) -------------
// grid: N*64*4 blocks, one per (n, k, c-quarter); 256 threads; thread owns 4
// pixels. Plain stores.
__global__ __launch_bounds__(256) void nv_resid_kernel(
    const float* __restrict__ x,          // [N,128,1024]
    const float* __restrict__ centroids,  // [68,128]
    const float* __restrict__ sa,         // [N,68,1024]
    const float* __restrict__ rnorm,      // [N,1024]
    float* __restrict__ out)              // [N,64,128,1024]
{
    const int b  = blockIdx.x;
    const int n  = b >> 8;
    const int k  = (b >> 2) & 63;
    const int c0 = (b & 3) << 5;
    const int t  = threadIdx.x;

    const f4v rn4 = ((const f4v*)(rnorm + (size_t)n * PIMG))[t];
    const f4v a4  = ((const f4v*)(sa + ((size_t)n * KG + k) * PIMG))[t];
    const f4v ra  = rn4 * a4;   // out = x*(rn*a) - cent*a

    const float* cw = centroids + k * CCH + c0;      // uniform -> s_load
    const float* xb = x + (size_t)n * (CCH * PIMG) + (size_t)c0 * PIMG;
    float* ob = out + (((size_t)n * KR + k) * CCH + c0) * PIMG;

    #pragma unroll 8
    for (int c = 0; c < 32; ++c) {
        f4v xv = ((const f4v*)(xb + c * PIMG))[t];
        float ce = cw[c];
        f4v o = xv * ra - ce * a4;
        ((f4v*)(ob + c * PIMG))[t] = o;
    }
}

extern "C" void kernel_launch(void* const* d_in, const int* in_sizes, int n_in,
                              void* d_out, int out_size, void* d_ws, size_t ws_size,
                              hipStream_t stream) {
    const float* x         = (const float*)d_in[0];
    const float* conv_w    = (const float*)d_in[1];
    const float* centroids = (const float*)d_in[2];

    const int N = in_sizes[0] / (CCH * PIMG);   // 8

    float* out    = (float*)d_out;
    float* sa_out = out + (size_t)N * KR * CCH * PIMG;  // second tuple element
    float* rnorm  = (float*)d_ws;                        // N*1024 floats

    nv_assign_kernel<<<N * (PIMG / T1), 512, 0, stream>>>(x, conv_w, sa_out, rnorm);
    nv_resid_kernel<<<N * KR * 4, 256, 0, stream>>>(x, centroids, sa_out, rnorm, out);
}